// Round 4
// baseline (274.638 us; speedup 1.0000x reference)
//
#include <hip/hip_runtime.h>
#include <stdint.h>

// LSTMBaseline: 2-layer, 1-step LSTM (zero init state) + decoder on MI355X.
//   h0 = lstm(x; W_ih0, b_ih0+b_hh0)   M=16384, K=512,  H=1024
//   h1 = lstm(h0; W_ih1, b_ih1+b_hh1)  K=1024
//   out = h1 @ W_dec^T + b_dec         N=512 (f32 out)
// f32 inputs -> bf16 prepass (x, gate-packed W_ih{0,1}, W_dec) in d_ws, then
// 256-row 8-wave MFMA GEMMs with double-buffered LDS + counted-vmcnt prefetch
// (T3+T4) + setprio on MFMA clusters (T5). f-gate dead (c0=0), W_hh dead.

typedef __attribute__((ext_vector_type(8))) __bf16 bf16x8;
typedef __attribute__((ext_vector_type(8))) unsigned short u16x8;
typedef __attribute__((ext_vector_type(4))) float f32x4;

#define BM 256
#define BK 64

__device__ __forceinline__ unsigned short f2b(float f) {
    unsigned int x = __builtin_bit_cast(unsigned int, f);
    x = x + 0x7FFFu + ((x >> 16) & 1u);   // RNE
    return (unsigned short)(x >> 16);
}
__device__ __forceinline__ float sigf(float x) { return 1.0f / (1.0f + __expf(-x)); }
__device__ __forceinline__ float tanh_safe(float x) {
    float a = fabsf(x);
    float e = __expf(-2.0f * a);
    float t = (1.0f - e) / (1.0f + e);
    return x < 0.0f ? -t : t;
}

__device__ __forceinline__ void cvt8(const float* __restrict__ s,
                                     unsigned short* __restrict__ d) {
    f32x4 lo = *reinterpret_cast<const f32x4*>(s);
    f32x4 hi = *reinterpret_cast<const f32x4*>(s + 4);
    u16x8 v;
    v[0] = f2b(lo[0]); v[1] = f2b(lo[1]); v[2] = f2b(lo[2]); v[3] = f2b(lo[3]);
    v[4] = f2b(hi[0]); v[5] = f2b(hi[1]); v[6] = f2b(hi[2]); v[7] = f2b(hi[3]);
    *reinterpret_cast<u16x8*>(d) = v;
}

__device__ __forceinline__ void gload16(const void* g, void* l) {
    __builtin_amdgcn_global_load_lds(
        (const __attribute__((address_space(1))) void*)g,
        (__attribute__((address_space(3))) void*)l,
        16, 0, 0);
}

// ---- pre-pass: f32 -> bf16 linear convert ---------------------------------
__global__ __launch_bounds__(256) void cvt_lin(const float* __restrict__ s,
                                               unsigned short* __restrict__ d,
                                               int n8) {
    int stride = gridDim.x * blockDim.x;
    for (int c = blockIdx.x * blockDim.x + threadIdx.x; c < n8; c += stride)
        cvt8(s + (size_t)c * 8, d + (size_t)c * 8);
}

// ---- pre-pass: gate-pack W (4H x K f32) -> (H/64 groups x 192 x K) bf16 ----
// Packed row p: group=p/192, r=p%192, wc=r/48, gate=(r%48)>>4 -> {i,g,o},
// hcol = group*64 + wc*16 + (r&15); src row = {0,2H,3H}[gate] + hcol.
// Matches the GEMM's B-tile row order (wave wc, fragment n == gate).
__global__ __launch_bounds__(256) void pack_w(const float* __restrict__ W,
                                              unsigned short* __restrict__ d,
                                              int K8, int H, int n8) {
    int stride = gridDim.x * blockDim.x;
    for (int c = blockIdx.x * blockDim.x + threadIdx.x; c < n8; c += stride) {
        int dstRow = c / K8, kc = c - dstRow * K8;
        int group = dstRow / 192, r = dstRow - group * 192;
        int wc = r / 48, rr = r - wc * 48;
        int gate = rr >> 4;
        int goff = (gate == 0) ? 0 : (gate + 1);
        int hcol = group * 64 + wc * 16 + (rr & 15);
        cvt8(W + ((size_t)(goff * H + hcol) * K8 + kc) * 8, d + (size_t)c * 8);
    }
}

// ---- fused GEMM, 256-row tile, 8 waves (2M x 4N), dbuf + counted vmcnt ----
// GATED=1 (NF=3): B tile 192 rows = 4 waves x {i,g,o} x 16 hcols; per-lane
//   activation epilogue, bf16 h out. GATED=0 (NF=2): plain GEMM+bias, f32 out.
template <int GATED, int NF>
__global__ __launch_bounds__(512, 1) void gemm_fused(
    const unsigned short* __restrict__ A,   // M x K bf16
    const unsigned short* __restrict__ Wp,  // packed (gated) / linear bf16
    const float* __restrict__ b0,
    const float* __restrict__ b1,
    void* __restrict__ Ov,
    int M, int K, int N, int NBX)
{
    constexpr int BROWS = NF * 64;          // B tile rows (192 / 128)
    constexpr int WNS   = NF * 16;          // wave B-row span (48 / 32)
    constexpr int ONB   = GATED ? 64 : 128; // output cols per block

    __shared__ __align__(16) unsigned short sA[2][BM * BK];
    __shared__ __align__(16) unsigned short sB[2][BROWS * BK];

    const int tid  = threadIdx.x;
    const int lane = tid & 63;
    const int w    = tid >> 6;
    const int wr   = w >> 2, wc = w & 3;
    const int l16  = lane & 15, hi8 = lane >> 4;

    // Bijective XCD swizzle (grids are multiples of 8): consecutive rid on an
    // XCD share the A row-panel -> L2 locality.
    const int cpx  = gridDim.x >> 3;
    const int orig = blockIdx.x;
    const int rid  = (orig & 7) * cpx + (orig >> 3);
    const int bx   = rid % NBX;
    const int by   = rid / NBX;
    const int row0 = by * BM;
    const int n0   = bx * ONB;

    // Staging: chunk ch -> (row r=ch>>3, slot=ch&7); LDS linear dest, global
    // source pre-swizzled (physical slot p holds logical slot p^(r&7)).
    const unsigned short* pA[4]; int dA[4];
#pragma unroll
    for (int i = 0; i < 4; ++i) {
        int ch = tid + i * 512, r = ch >> 3, slot = ch & 7, ls = slot ^ (r & 7);
        dA[i] = ch * 8;
        pA[i] = A + (size_t)(row0 + r) * K + ls * 8;
    }
    const unsigned short* pB[NF]; int dB[NF];
#pragma unroll
    for (int i = 0; i < NF; ++i) {
        int ch = tid + i * 512, r = ch >> 3, slot = ch & 7, ls = slot ^ (r & 7);
        dB[i] = ch * 8;
        int prow = GATED ? bx * BROWS + r : n0 + r;
        pB[i] = Wp + (size_t)prow * K + ls * 8;
    }

    // Issue one K-tile's staging loads (4+NF per thread) and advance pointers.
    auto issue = [&](int buf) {
#pragma unroll
        for (int i = 0; i < 4; ++i)  { gload16(pA[i], &sA[buf][dA[i]]); pA[i] += BK; }
#pragma unroll
        for (int i = 0; i < NF; ++i) { gload16(pB[i], &sB[buf][dB[i]]); pB[i] += BK; }
    };

    f32x4 acc[8][NF];
#pragma unroll
    for (int m = 0; m < 8; ++m)
#pragma unroll
        for (int n = 0; n < NF; ++n)
            acc[m][n] = (f32x4){0.f, 0.f, 0.f, 0.f};

    const int NT = K >> 6;   // K-tiles (>= 8 for all our shapes)
    issue(0);                // tile 0 -> buf 0
    issue(1);                // tile 1 -> buf 1
    int cur = 0;

    for (int t = 0; t < NT; ++t) {
        // Wait for tile t's loads only; tile t+1's (4+NF, issued later) stay
        // in flight across this tile's compute (T4 counted vmcnt).
        if (t + 1 < NT) {
            if constexpr (NF == 3) asm volatile("s_waitcnt vmcnt(7)" ::: "memory");
            else                   asm volatile("s_waitcnt vmcnt(6)" ::: "memory");
        } else {
            asm volatile("s_waitcnt vmcnt(0)" ::: "memory");
        }
        __builtin_amdgcn_sched_barrier(0);
        __builtin_amdgcn_s_barrier();   // all waves' tile-t loads landed

        const unsigned short* sAc = sA[cur];
        const unsigned short* sBc = sB[cur];
#pragma unroll
        for (int ks = 0; ks < 2; ++ks) {
            bf16x8 av[8], bv[NF];
#pragma unroll
            for (int m = 0; m < 8; ++m) {
                int row = wr * 128 + m * 16 + l16;
                int ps = (ks * 4 + hi8) ^ (row & 7);
                av[m] = *reinterpret_cast<const bf16x8*>(sAc + row * BK + ps * 8);
            }
#pragma unroll
            for (int n = 0; n < NF; ++n) {
                int row = wc * WNS + n * 16 + l16;
                int ps = (ks * 4 + hi8) ^ (row & 7);
                bv[n] = *reinterpret_cast<const bf16x8*>(sBc + row * BK + ps * 8);
            }
            __builtin_amdgcn_s_setprio(1);
#pragma unroll
            for (int m = 0; m < 8; ++m)
#pragma unroll
                for (int n = 0; n < NF; ++n)
                    acc[m][n] = __builtin_amdgcn_mfma_f32_16x16x32_bf16(
                        av[m], bv[n], acc[m][n], 0, 0, 0);
            __builtin_amdgcn_s_setprio(0);
        }
        // Drain this wave's ds_reads, then release the buffer for overwrite.
        asm volatile("s_waitcnt lgkmcnt(0)" ::: "memory");
        __builtin_amdgcn_sched_barrier(0);
        __builtin_amdgcn_s_barrier();
        if (t + 2 < NT) issue(cur);     // refill the buffer just freed
        cur ^= 1;
    }

    // ---- epilogue ----
    if constexpr (GATED) {
        unsigned short* O = (unsigned short*)Ov;
        const int hcol = n0 + wc * 16 + l16;    // fragment col n == gate
        const float bi = b0[hcol]         + b1[hcol];
        const float bg = b0[2 * N + hcol] + b1[2 * N + hcol];
        const float bo = b0[3 * N + hcol] + b1[3 * N + hcol];
#pragma unroll
        for (int m = 0; m < 8; ++m) {
            int rbase = row0 + wr * 128 + m * 16 + hi8 * 4;
#pragma unroll
            for (int q = 0; q < 4; ++q) {
                float iv = sigf(acc[m][0][q] + bi);
                float gv = tanh_safe(acc[m][1][q] + bg);
                float ov = sigf(acc[m][2][q] + bo);
                float h  = ov * tanh_safe(iv * gv);
                O[(size_t)(rbase + q) * N + hcol] = f2b(h);
            }
        }
    } else {
        float* O = (float*)Ov;
#pragma unroll
        for (int n = 0; n < NF; ++n) {
            int col = n0 + wc * WNS + n * 16 + l16;
            float bias = b0[col];
#pragma unroll
            for (int m = 0; m < 8; ++m) {
                int rbase = row0 + wr * 128 + m * 16 + hi8 * 4;
#pragma unroll
                for (int q = 0; q < 4; ++q)
                    O[(size_t)(rbase + q) * N + col] = acc[m][n][q] + bias;
            }
        }
    }
}

extern "C" void kernel_launch(void* const* d_in, const int* in_sizes, int n_in,
                              void* d_out, int out_size, void* d_ws, size_t ws_size,
                              hipStream_t stream) {
    constexpr int M = 16384, D = 512, H = 1024;

    const float* x    = (const float*)d_in[0];
    const float* Wih0 = (const float*)d_in[1];
    // d_in[2] = W_hh0: unused (h0 = 0)
    const float* bih0 = (const float*)d_in[3];
    const float* bhh0 = (const float*)d_in[4];
    const float* Wih1 = (const float*)d_in[5];
    // d_in[6] = W_hh1: unused
    const float* bih1 = (const float*)d_in[7];
    const float* bhh1 = (const float*)d_in[8];
    const float* Wdec = (const float*)d_in[9];
    const float* bdec = (const float*)d_in[10];

    const size_t szH = (size_t)M * H * 2;          // 33.5 MB
    const size_t sw0 = (size_t)3 * H * D * 2;      // 3.1 MB
    const size_t sw1 = (size_t)3 * H * H * 2;      // 6.3 MB

    unsigned short* h0 = (unsigned short*)d_ws;
    unsigned short* h1 = (unsigned short*)((char*)d_ws + szH);
    unsigned short* xb = h1;                       // alias: dead before L1 writes h1
    unsigned short* wp0   = (unsigned short*)((char*)d_ws + 2 * szH);
    unsigned short* wp1   = (unsigned short*)((char*)wp0 + sw0);
    unsigned short* wdecb = (unsigned short*)((char*)wp1 + sw1);
    // ws requirement (~77.5 MB) verified available at runtime in round 3.

    cvt_lin<<<2048, 256, 0, stream>>>(x, xb, M * D / 8);
    pack_w <<<768,  256, 0, stream>>>(Wih0, wp0, D / 8, H, 3 * H * D / 8);
    pack_w <<<1536, 256, 0, stream>>>(Wih1, wp1, H / 8, H, 3 * H * H / 8);
    cvt_lin<<<256,  256, 0, stream>>>(Wdec, wdecb, D * H / 8);

    // layer 0: K=512; grid = (H/64) x (M/256) = 16 x 64 = 1024 blocks
    gemm_fused<1, 3><<<dim3((H / 64) * (M / BM)), 512, 0, stream>>>(
        xb, wp0, bih0, bhh0, h0, M, D, H, H / 64);
    // layer 1: K=1024
    gemm_fused<1, 3><<<dim3((H / 64) * (M / BM)), 512, 0, stream>>>(
        h0, wp1, bih1, bhh1, h1, M, H, H, H / 64);
    // decoder: N=512; grid = (D/128) x (M/256) = 4 x 64 = 256 blocks
    gemm_fused<0, 2><<<dim3((D / 128) * (M / BM)), 512, 0, stream>>>(
        h1, wdecb, bdec, nullptr, (float*)d_out, M, H, D, D / 128);
}